// Round 6
// baseline (404.146 us; speedup 1.0000x reference)
//
#include <hip/hip_runtime.h>

// Heat equation, 2 materials, N=512, 499 steps, all frames written.
// Temporal tiling: K=16 steps/launch, 32 dispatches, 1024-thread blocks.
// R6: vertical 4x1 strips — wave = 4-row x 64-col slab (lane = column).
// State lives entirely in registers; left/right via DPP lane shifts (VALU
// pipe); only slab boundary rows cross waves via LDS: ONE ds_write2_b32 +
// ONE ds_read2_b32 per wave per step (read prefetched a full step ahead).
// LDS-only per-step barrier (no vmcnt drain) keeps frame stores async.

#define GN 512
#define NSTEPS 499
#define MBND 256
#define INV_DX2 261121.0f     // 511^2 = 1/dx^2
#define DT 5e-7f

#define TO 32                 // owned tile edge
#define KMAX 16               // halo width = steps per launch
#define RPT 4                 // rows per thread (strip height)
#define PSTRIDE (18 * 2 * 64) // floats per parity buffer (with guard groups)

__device__ __forceinline__ void lds_barrier() {
    // LDS-visibility-only workgroup barrier: do NOT drain vmcnt (global
    // frame stores stay in flight across steps).
    asm volatile("s_waitcnt lgkmcnt(0)" ::: "memory");
    __builtin_amdgcn_s_barrier();
    asm volatile("" ::: "memory");
}

// lane i <- lane i-1 (wave_shr:1). bound_ctrl=0 with old=src: lane 0 keeps
// its own value (junk-safe: region edge, outside validity trapezoid).
__device__ __forceinline__ float dpp_shr1(float x) {
    int v = __builtin_amdgcn_update_dpp(__float_as_int(x), __float_as_int(x),
                                        0x138, 0xf, 0xf, false);
    return __int_as_float(v);
}
// lane i <- lane i+1 (wave_shl:1)
__device__ __forceinline__ float dpp_shl1(float x) {
    int v = __builtin_amdgcn_update_dpp(__float_as_int(x), __float_as_int(x),
                                        0x130, 0xf, 0xf, false);
    return __int_as_float(v);
}

template<int STEPS>
__global__ __launch_bounds__(1024) void heat_multi(
    const float* __restrict__ Tin, float* __restrict__ outBase,
    const float* __restrict__ k1p, const float* __restrict__ k2p,
    const float* __restrict__ a1p, const float* __restrict__ a2p)
{
    // [parity][group g stored at g+1; 0 and 17 are never-written guards]
    // [0]=slab top row, [1]=slab bottom row, [col]
    __shared__ float S[2][18][2][64];

    const int t    = threadIdx.x;            // 0..1023
    const int lane = t & 63;                 // column within 64-wide region
    const int ty   = t >> 6;                 // row-group == wave id, 0..15
    const int bi = blockIdx.x >> 4;          // 16x16 tile grid
    const int bj = blockIdx.x & 15;
    const int gi0 = bi * TO - KMAX;
    const int gj0 = bj * TO - KMAX;
    const int gj  = gj0 + lane;              // this thread's global column
    const int gr0 = gi0 + ty * RPT;          // first global row of strip

    const float k1 = k1p[0], k2 = k2p[0];
    const float a1 = a1p[0], a2 = a2p[0];
    const float invk = 1.0f / (k1 + k2);
    const float Ac = (DT * INV_DX2) * ((gj < MBND) ? a1 : a2);
    const bool ifcc = (gj == MBND - 1);
    const bool bcc  = (gj <= 0) || (gj >= GN - 1);
    bool brow[RPT];
    #pragma unroll
    for (int r = 0; r < RPT; ++r) {
        const int gi = gr0 + r;
        brow[r] = (gi <= 0) || (gi >= GN - 1);
    }

    // block-uniform specialization (scalar branches)
    const bool anyIfc = (bj == 7) || (bj == 8);
    const bool anyBC  = (bj == 0) || (bj == 15);
    const bool anyBR  = (bi == 0) || (bi == 15);

    // ---- initial state straight from global: 6 coalesced dword loads
    const bool vc = ((unsigned)gj < GN);
    float R[RPT], tN, bN;
    #pragma unroll
    for (int r = 0; r < RPT; ++r) {
        const int gi = gr0 + r;
        R[r] = (vc && (unsigned)gi < GN) ? Tin[(long)gi * GN + gj] : 0.0f;
    }
    { const int gi = gr0 - 1;   tN = (vc && (unsigned)gi < GN) ? Tin[(long)gi * GN + gj] : 0.0f; }
    { const int gi = gr0 + RPT; bN = (vc && (unsigned)gi < GN) ? Tin[(long)gi * GN + gj] : 0.0f; }

    // LDS bases; parity becomes a compile-time float-index offset that the
    // compiler folds into the 16-bit DS immediate (max 9984B < 64K).
    float*       wp = &S[0][ty + 1][0][lane];   // wp[0]=top, wp[64]=bottom
    const float* rp = &S[0][ty][1][lane];       // rp[0]=tN,  rp[192]=bN

    // store addressing: rows 0,1 off d0 (imm 0/2048B), rows 2,3 off d2
    const bool own = (ty >= 4) && (ty < 12) && (lane >= 16) && (lane < 48);
    float* d0 = outBase + ((long)gr0 * GN + gj);
    float* d2 = d0 + 2L * GN;

    #pragma unroll
    for (int s = 1; s <= STEPS; ++s) {
        const int p = (s & 1) * PSTRIDE;

        // boundary rows first: they feed the LDS exchange
        const float lf0 = dpp_shr1(R[0]), rt0 = dpp_shl1(R[0]);
        const float lf3 = dpp_shr1(R[3]), rt3 = dpp_shl1(R[3]);
        float N0 = fmaf(Ac, fmaf(-4.0f, R[0], (tN   + R[1]) + (lf0 + rt0)), R[0]);
        float N3 = fmaf(Ac, fmaf(-4.0f, R[3], (R[2] + bN  ) + (lf3 + rt3)), R[3]);
        if (anyIfc) {   // interface column from OLD T neighbors
            N0 = ifcc ? (k1 * rt0 + k2 * lf0) * invk : N0;
            N3 = ifcc ? (k1 * rt3 + k2 * lf3) * invk : N3;
        }
        if (anyBC) { N0 = bcc ? 0.0f : N0;     N3 = bcc ? 0.0f : N3; }
        if (anyBR) { N0 = brow[0] ? 0.0f : N0; N3 = brow[3] ? 0.0f : N3; }

        if (s < STEPS) { wp[p] = N0; wp[p + 64] = N3; }   // -> ds_write2_b32

        // interior rows: pure register compute (hides the write latency)
        const float lf1 = dpp_shr1(R[1]), rt1 = dpp_shl1(R[1]);
        const float lf2 = dpp_shr1(R[2]), rt2 = dpp_shl1(R[2]);
        float N1 = fmaf(Ac, fmaf(-4.0f, R[1], (R[0] + R[2]) + (lf1 + rt1)), R[1]);
        float N2 = fmaf(Ac, fmaf(-4.0f, R[2], (R[1] + R[3]) + (lf2 + rt2)), R[2]);
        if (anyIfc) {
            N1 = ifcc ? (k1 * rt1 + k2 * lf1) * invk : N1;
            N2 = ifcc ? (k1 * rt2 + k2 * lf2) * invk : N2;
        }
        if (anyBC) { N1 = bcc ? 0.0f : N1;     N2 = bcc ? 0.0f : N2; }
        if (anyBR) { N1 = brow[1] ? 0.0f : N1; N2 = brow[2] ? 0.0f : N2; }

        // stream owned strip (async; never drained by the per-step barrier)
        if (own) { d0[0] = N0; d0[GN] = N1; d2[0] = N2; d2[GN] = N3; }
        d0 += (long)GN * GN; d2 += (long)GN * GN;

        R[0] = N0; R[1] = N1; R[2] = N2; R[3] = N3;

        if (s < STEPS) {
            lds_barrier();                    // drains only our ds_write2
            // prefetch next step's neighbor rows (-> ds_read2_b32);
            // consumed at the TOP of the next iteration = full-step hiding
            tN = rp[p];
            bN = rp[p + 192];
        }
    }
}

extern "C" void kernel_launch(void* const* d_in, const int* in_sizes, int n_in,
                              void* d_out, int out_size, void* d_ws, size_t ws_size,
                              hipStream_t stream)
{
    const float* u0 = (const float*)d_in[0];
    const float* k1 = (const float*)d_in[1];
    const float* k2 = (const float*)d_in[2];
    const float* a1 = (const float*)d_in[3];
    const float* a2 = (const float*)d_in[4];
    float* out = (float*)d_out;

    const int pts = GN * GN;
    const float* src = u0;
    int done = 0;
    while (done < NSTEPS) {
        int steps = NSTEPS - done;
        if (steps > KMAX) steps = KMAX;
        float* ob = out + (size_t)done * pts;
        if (steps == KMAX)
            heat_multi<KMAX><<<256, 1024, 0, stream>>>(src, ob, k1, k2, a1, a2);
        else  // NSTEPS = 31*16 + 3 -> remainder is always 3
            heat_multi<3><<<256, 1024, 0, stream>>>(src, ob, k1, k2, a1, a2);
        src = ob + (size_t)(steps - 1) * pts;
        done += steps;
    }
}